// Round 8
// baseline (753.992 us; speedup 1.0000x reference)
//
#include <hip/hip_runtime.h>
#include <hip/hip_bf16.h>

typedef __bf16 bf16x8 __attribute__((ext_vector_type(8)));
typedef float f32x4 __attribute__((ext_vector_type(4)));

__device__ __forceinline__ float bf2f(unsigned int u) {
    unsigned int x = u << 16;
    return __builtin_bit_cast(float, x);
}
__device__ __forceinline__ unsigned short f2bf(float f) {
    unsigned int x = __builtin_bit_cast(unsigned int, f);
    x += 0x7fffu + ((x >> 16) & 1u);   // RNE
    return (unsigned short)(x >> 16);
}

__device__ __forceinline__ void gld_lds16(const unsigned short* g, unsigned short* s) {
    __builtin_amdgcn_global_load_lds((const __attribute__((address_space(1))) void*)g,
                                     (__attribute__((address_space(3))) void*)s, 16, 0, 0);
}

// ---------------------------------------------------------------------------
// 256x128 ring GEMM @ 2 blocks/CU: C[m,n] = sum_k A[m,k]*B[n,k] + bias[n].
// 8 waves (4M x 2N), 512 threads, BK unit = 32, 3-slot LDS ring (72 KiB
// dynamic) -> 2 co-resident blocks/CU.
//
// WHY (r7 post-mortem): at 1 block/CU every schedule variant (r1/r3/r6/r7)
// serializes the LDS-port phase and the matrix phase of the SAME block
// (sum-model, ~3700 cyc/unit). m114 (HW-measured): waves of DIFFERENT
// blocks overlap MFMA and memory phases fully — co-residency converts the
// sum to a max. r5 proved the tile+occupancy works (Occ 44%) but its
// bn-major mapping thrashed HBM (799 MB). This round = r5 kernel verbatim
// + r6's verified bm-major XCD-chunked mapping (188 MB regime).
//
// Ring ledger (r5 harness-verified, unchanged):
//  - unit u reads slot u%3; stages unit u+2 into slot (u+2)%3 == (u-1)%3,
//    whose reads all drained before the close barrier of unit u-1.
//  - close: s_waitcnt vmcnt(3) retires this wave's 3 loads of unit u+1
//    (3 loads of u+2 stay in flight); s_barrier makes it collective.
//  - post-loop vmcnt(0): no LDS-writing load in flight at endpgm.
//
// LDS slot (24 KiB): A = regions 0..15 (256 rows), B = regions 16..23
// (128 rows); region = 16 rows x 32 cols (1 KiB). Swizzle: phys 16B-slot =
// (row&7)|(kquad<<3)|((row>>3)<<5), realized by permuting the GLOBAL source
// lane mapping (gld_lds dest linear); same map on reads -> 0 conflicts
// (measured r1-r7).
//
// Block mapping: XCD-chunked bm-major (bm = L/nbn, bn = L%nbn): each XCD
// owns a contiguous bm band and walks bn-fast; A-tile stays L2-hot for its
// nbn consecutive uses; B panels (6 MB total) are L3-resident.
// ---------------------------------------------------------------------------
template<bool OUT_F32>
__global__ __launch_bounds__(512, 4) void gemm256x128(
    const unsigned short* __restrict__ A, int lda,
    const unsigned short* __restrict__ B,
    const float* __restrict__ bias,
    void* __restrict__ C, int N, int K, int nbn)
{
    extern __shared__ char smem[];
    const int tid   = threadIdx.x;
    const int lane  = tid & 63;
    const int wave  = tid >> 6;                // 0..7
    const int wm    = (wave >> 1) * 64;        // 4 M-positions over 256 rows
    const int wn    = (wave & 1) * 64;         // 2 N-positions over 128 cols
    const int lrow  = lane & 15;
    const int lquad = lane >> 4;

    // XCD-chunked, bm-major (gridDim.x % 8 == 0 for all our launches)
    int L = (int)blockIdx.x;
    L = (L & 7) * ((int)gridDim.x >> 3) + (L >> 3);
    const long bm = (long)(L / nbn) * 256;
    const long bn = (long)(L % nbn) * 128;

    // staging source mapping (inverse of the read swizzle):
    // lane -> row-in-region = (lane&7) + ((lane>>5)<<3), kquad = (lane>>3)&3
    const int srow = (lane & 7) + ((lane >> 5) << 3);
    const int scol = ((lane >> 3) & 3) * 8;
    // wave w stages regions {w, 8+w, 16+w}: A rows 16w.., A rows 128+16w.., B rows 16w..
    const unsigned short* Ag0 = A + (bm + wave * 16 + srow) * (long)lda + scol;
    const unsigned short* Ag1 = A + (bm + 128 + wave * 16 + srow) * (long)lda + scol;
    const unsigned short* Bg0 = B + (bn + wave * 16 + srow) * (long)K + scol;

    // linear LDS dest byte offsets within a slot (wave-uniform base + lane*16)
    const int dA0 = wave * 1024 + lane * 16;
    const int dA1 = (8 + wave) * 1024 + lane * 16;
    const int dB0 = (16 + wave) * 1024 + lane * 16;

    // swizzled read offset within a region
    const int rdoff = (lrow & 7) * 16 + (lrow >> 3) * 512 + lquad * 128;

    f32x4 acc[4][4];
#pragma unroll
    for (int i = 0; i < 4; i++)
#pragma unroll
        for (int j = 0; j < 4; j++)
            acc[i][j] = (f32x4){0.f, 0.f, 0.f, 0.f};

    const int NU = K >> 5;   // K units of 32 (requires NU >= 3)

    auto stage = [&](int su, char* sb) {
        gld_lds16(Ag0 + su * 32, (unsigned short*)(sb + dA0));
        gld_lds16(Ag1 + su * 32, (unsigned short*)(sb + dA1));
        gld_lds16(Bg0 + su * 32, (unsigned short*)(sb + dB0));
    };

    // prologue: stage units 0,1 into slots 0,1; wait only for unit 0
    stage(0, smem);
    stage(1, smem + 24576);
    asm volatile("s_waitcnt vmcnt(3)\n\ts_barrier" ::: "memory");

    int cs = 0, ws = 2;      // current read slot, stage dest slot
    for (int u = 0; u < NU; ++u) {
        const char* sl = smem + cs * 24576;
        char* sw = smem + ws * 24576;
        const int us = (u + 2 < NU) ? (u + 2) : (NU - 1);  // clamped tail stage
        bf16x8 af[4], bq[4];

#pragma unroll
        for (int j = 0; j < 4; j++)
            bq[j] = *(const bf16x8*)(sl + 16384 + ((wn >> 4) + j) * 1024 + rdoff);
#pragma unroll
        for (int i = 0; i < 4; i++)
            af[i] = *(const bf16x8*)(sl + ((wm >> 4) + i) * 1024 + rdoff);
        stage(us, sw);

        __builtin_amdgcn_s_setprio(1);
#pragma unroll
        for (int i = 0; i < 4; i++)
#pragma unroll
            for (int j = 0; j < 4; j++)
                acc[i][j] = __builtin_amdgcn_mfma_f32_16x16x32_bf16(bq[j], af[i], acc[i][j], 0, 0, 0);
        __builtin_amdgcn_s_setprio(0);

        // counted close: unit u+2 stays in flight; unit u+1 is landed
        asm volatile("s_waitcnt vmcnt(3)\n\ts_barrier" ::: "memory");
        cs = (cs == 2) ? 0 : cs + 1;
        ws = (ws == 2) ? 0 : ws + 1;
    }

    // drain clamped tail stages: no LDS-writing load in flight at endpgm
    asm volatile("s_waitcnt vmcnt(0)" ::: "memory");

    // Swapped C/D layout: M-row = lane&15 (+i*16), N-col = quad*4 + reg (+j*16).
#pragma unroll
    for (int i = 0; i < 4; i++) {
        const long row = bm + wm + i * 16 + lrow;
#pragma unroll
        for (int j = 0; j < 4; j++) {
            const int colb = (int)bn + wn + j * 16 + lquad * 4;
            float4 b4 = bias ? ((const float4*)bias)[colb >> 2]
                             : make_float4(0.f, 0.f, 0.f, 0.f);
            const float v0 = acc[i][j][0] + b4.x;
            const float v1 = acc[i][j][1] + b4.y;
            const float v2 = acc[i][j][2] + b4.z;
            const float v3 = acc[i][j][3] + b4.w;
            if (OUT_F32) {
                *(float4*)&((float*)C)[row * (long)N + colb] = make_float4(v0, v1, v2, v3);
            } else {
                unsigned int lo = (unsigned int)f2bf(v0) | ((unsigned int)f2bf(v1) << 16);
                unsigned int hi = (unsigned int)f2bf(v2) | ((unsigned int)f2bf(v3) << 16);
                *(uint2*)&((unsigned short*)C)[row * (long)N + colb] = make_uint2(lo, hi);
            }
        }
    }
}

// ---------------------------------------------------------------------------
// legacy 128x128 GEMM (m97 structure) — kept for the small weight-fusion GEMM
// ---------------------------------------------------------------------------
template<bool OUT_F32>
__global__ __launch_bounds__(256) void gemm_bt(
    const unsigned short* __restrict__ A, int lda,
    const unsigned short* __restrict__ B,
    const unsigned short* __restrict__ B2, long bsplit,
    const float* __restrict__ bias,
    void* __restrict__ C, int N, int K)
{
    __shared__ unsigned short As[128 * 32];
    __shared__ unsigned short Bs[128 * 32];
    const int tid   = threadIdx.x;
    const int lane  = tid & 63;
    const int wave  = tid >> 6;
    const int wm    = (wave >> 1) * 64;
    const int wn    = (wave & 1) * 64;
    const int lrow  = lane & 15;
    const int lquad = lane >> 4;
    const long bm = (long)blockIdx.y * 128;
    const long bn = (long)blockIdx.x * 128;
    const unsigned short* Bp = (bm >= bsplit) ? B2 : B;

    f32x4 acc[4][4];
#pragma unroll
    for (int i = 0; i < 4; i++)
#pragma unroll
        for (int j = 0; j < 4; j++)
            acc[i][j] = (f32x4){0.f, 0.f, 0.f, 0.f};

    const int r0 = tid >> 2;
    const int c0 = (tid & 3) * 8;
    const unsigned short* Ag0 = A + (bm + r0) * (long)lda + c0;
    const unsigned short* Ag1 = A + (bm + r0 + 64) * (long)lda + c0;
    const unsigned short* Bg0 = Bp + (bn + r0) * (long)K + c0;
    const unsigned short* Bg1 = Bp + (bn + r0 + 64) * (long)K + c0;
    unsigned short* As0 = &As[tid * 8];
    unsigned short* As1 = &As[tid * 8 + 2048];
    unsigned short* Bs0 = &Bs[tid * 8];
    unsigned short* Bs1 = &Bs[tid * 8 + 2048];

    for (int k0 = 0; k0 < K; k0 += 32) {
        gld_lds16(Ag0 + k0, As0);
        gld_lds16(Ag1 + k0, As1);
        gld_lds16(Bg0 + k0, Bs0);
        gld_lds16(Bg1 + k0, Bs1);
        __syncthreads();
        bf16x8 af[4], bq[4];
#pragma unroll
        for (int i = 0; i < 4; i++)
            af[i] = *(const bf16x8*)&As[(wm + i * 16 + lrow) * 32 + lquad * 8];
#pragma unroll
        for (int j = 0; j < 4; j++)
            bq[j] = *(const bf16x8*)&Bs[(wn + j * 16 + lrow) * 32 + lquad * 8];
#pragma unroll
        for (int i = 0; i < 4; i++)
#pragma unroll
            for (int j = 0; j < 4; j++)
                acc[i][j] = __builtin_amdgcn_mfma_f32_16x16x32_bf16(bq[j], af[i], acc[i][j], 0, 0, 0);
        __syncthreads();
    }

#pragma unroll
    for (int i = 0; i < 4; i++) {
        const long row = bm + wm + i * 16 + lrow;
#pragma unroll
        for (int j = 0; j < 4; j++) {
            const int colb = (int)bn + wn + j * 16 + lquad * 4;
            float4 b4 = bias ? ((const float4*)bias)[colb >> 2]
                             : make_float4(0.f, 0.f, 0.f, 0.f);
            const float v0 = acc[i][j][0] + b4.x;
            const float v1 = acc[i][j][1] + b4.y;
            const float v2 = acc[i][j][2] + b4.z;
            const float v3 = acc[i][j][3] + b4.w;
            if (OUT_F32) {
                *(float4*)&((float*)C)[row * (long)N + colb] = make_float4(v0, v1, v2, v3);
            } else {
                unsigned int lo = (unsigned int)f2bf(v0) | ((unsigned int)f2bf(v1) << 16);
                unsigned int hi = (unsigned int)f2bf(v2) | ((unsigned int)f2bf(v3) << 16);
                *(uint2*)&((unsigned short*)C)[row * (long)N + colb] = make_uint2(lo, hi);
            }
        }
    }
}

// Per (group,head): 4x4 scores over hd=128, diag masked, softmax, o = A@v.
__global__ __launch_bounds__(256) void attn4(
    const unsigned short* __restrict__ QKV,  // [M][3072]: q|k|v
    unsigned short* __restrict__ O)          // [M][1024]
{
    const int wave = threadIdx.x >> 6;
    const int lane = threadIdx.x & 63;
    const int half = lane >> 5;
    const int l    = lane & 31;
    const int gh = blockIdx.x * 8 + wave * 2 + half;  // 0..65535
    const int g = gh >> 3, h = gh & 7;
    const long row0 = (long)g * 4;
    const int d0 = h * 128 + l * 4;
    const float scale = 0.08838834764831845f;  // 1/sqrt(128)

    float q[4][4], k[4][4], v[4][4];
#pragma unroll
    for (int i = 0; i < 4; i++) {
        const unsigned short* base = QKV + (row0 + i) * 3072 + d0;
        uint2 uq = *(const uint2*)base;
        uint2 uk = *(const uint2*)(base + 1024);
        uint2 uv = *(const uint2*)(base + 2048);
        q[i][0] = bf2f(uq.x & 0xffffu); q[i][1] = bf2f(uq.x >> 16);
        q[i][2] = bf2f(uq.y & 0xffffu); q[i][3] = bf2f(uq.y >> 16);
        k[i][0] = bf2f(uk.x & 0xffffu); k[i][1] = bf2f(uk.x >> 16);
        k[i][2] = bf2f(uk.y & 0xffffu); k[i][3] = bf2f(uk.y >> 16);
        v[i][0] = bf2f(uv.x & 0xffffu); v[i][1] = bf2f(uv.x >> 16);
        v[i][2] = bf2f(uv.y & 0xffffu); v[i][3] = bf2f(uv.y >> 16);
    }
    float s[4][4];
#pragma unroll
    for (int i = 0; i < 4; i++)
#pragma unroll
        for (int j = 0; j < 4; j++)
            s[i][j] = q[i][0] * k[j][0] + q[i][1] * k[j][1]
                    + q[i][2] * k[j][2] + q[i][3] * k[j][3];
#pragma unroll
    for (int m = 1; m < 32; m <<= 1)
#pragma unroll
        for (int i = 0; i < 4; i++)
#pragma unroll
            for (int j = 0; j < 4; j++)
                s[i][j] += __shfl_xor(s[i][j], m, 64);

#pragma unroll
    for (int i = 0; i < 4; i++) {
        float mx = -3.0e38f;
#pragma unroll
        for (int j = 0; j < 4; j++)
            if (j != i) mx = fmaxf(mx, s[i][j] * scale);
        float p[4], den = 0.f;
#pragma unroll
        for (int j = 0; j < 4; j++) {
            p[j] = (j == i) ? 0.f : __expf(s[i][j] * scale - mx);
            den += p[j];
        }
        const float inv = 1.f / den;
        float o0 = 0.f, o1 = 0.f, o2 = 0.f, o3 = 0.f;
#pragma unroll
        for (int j = 0; j < 4; j++) {
            const float a = p[j] * inv;
            o0 += a * v[j][0]; o1 += a * v[j][1];
            o2 += a * v[j][2]; o3 += a * v[j][3];
        }
        unsigned int lo = (unsigned int)f2bf(o0) | ((unsigned int)f2bf(o1) << 16);
        unsigned int hi = (unsigned int)f2bf(o2) | ((unsigned int)f2bf(o3) << 16);
        *(uint2*)(O + (row0 + i) * 1024 + d0) = make_uint2(lo, hi);
    }
}

__global__ __launch_bounds__(256) void cvt_bf16(const float* __restrict__ in,
                                                unsigned short* __restrict__ out, int n4)
{
    int i = blockIdx.x * blockDim.x + threadIdx.x;
    if (i >= n4) return;
    float4 v = ((const float4*)in)[i];
    unsigned int a = (unsigned int)f2bf(v.x) | ((unsigned int)f2bf(v.y) << 16);
    unsigned int b = (unsigned int)f2bf(v.z) | ((unsigned int)f2bf(v.w) << 16);
    ((uint2*)out)[i] = make_uint2(a, b);
}

// One dispatch for all weight prep:
//   blocks [0,4096)    : cvt win -> win16 (786432 f4) then wout -> wo16 (262144 f4)
//   blocks [4096,4608) : transpose+cvt wqk -> wqkT / wv -> wvT (64x64 tiles, n=1024)
//   blocks [4608,5376) : bbig[row] = dot(win[row,:], row<2048?bqk:bv) + bin[row]
__global__ __launch_bounds__(256) void prep_w(
    const float* __restrict__ win,  unsigned short* __restrict__ win16,
    const float* __restrict__ wout, unsigned short* __restrict__ wo16,
    const float* __restrict__ wqk,  unsigned short* __restrict__ wqkT,
    const float* __restrict__ wv,   unsigned short* __restrict__ wvT,
    const float* __restrict__ bqk,  const float* __restrict__ bv,
    const float* __restrict__ bin,  float* __restrict__ bbig)
{
    __shared__ unsigned short tile[64][65];
    const int bid = blockIdx.x;
    if (bid < 4096) {
        int i = bid * 256 + threadIdx.x;
        const float* in;
        unsigned short* out;
        int j;
        if (i < 786432) { in = win; out = win16; j = i; }
        else            { in = wout; out = wo16; j = i - 786432; }
        float4 v = ((const float4*)in)[j];
        unsigned int a = (unsigned int)f2bf(v.x) | ((unsigned int)f2bf(v.y) << 16);
        unsigned int b = (unsigned int)f2bf(v.z) | ((unsigned int)f2bf(v.w) << 16);
        ((uint2*)out)[j] = make_uint2(a, b);
    } else if (bid < 4608) {
        const int b2 = bid - 4096;
        const int z = b2 >> 8, rem = b2 & 255;
        const int bx = (rem & 15) * 64, by = (rem >> 4) * 64;
        const float* in = z ? wv : wqk;
        unsigned short* out = z ? wvT : wqkT;
        const int tx = threadIdx.x & 63, ty = threadIdx.x >> 6;
        for (int r = ty; r < 64; r += 4)
            tile[r][tx] = f2bf(in[(long)(by + r) * 1024 + bx + tx]);
        __syncthreads();
        for (int r = ty; r < 64; r += 4)
            out[(long)(bx + r) * 1024 + by + tx] = tile[tx][r];
    } else {
        const int row = (bid - 4608) * 4 + (threadIdx.x >> 6);
        const int lane = threadIdx.x & 63;
        const float* b = (row < 2048) ? bqk : bv;
        float s = 0.f;
        for (int t = lane; t < 1024; t += 64) s += win[(long)row * 1024 + t] * b[t];
#pragma unroll
        for (int m = 1; m < 64; m <<= 1) s += __shfl_xor(s, m, 64);
        if (lane == 0) bbig[row] = s + bin[row];
    }
}

extern "C" void kernel_launch(void* const* d_in, const int* in_sizes, int n_in,
                              void* d_out, int out_size, void* d_ws, size_t ws_size,
                              hipStream_t stream)
{
    (void)in_sizes; (void)n_in; (void)out_size; (void)ws_size;
    const float* x    = (const float*)d_in[0];
    const float* wqk  = (const float*)d_in[1];
    const float* bqk  = (const float*)d_in[2];
    const float* wv   = (const float*)d_in[3];
    const float* bv   = (const float*)d_in[4];
    const float* win  = (const float*)d_in[5];
    const float* bin  = (const float*)d_in[6];
    const float* wout = (const float*)d_in[7];
    const float* bout = (const float*)d_in[8];

    char* ws = (char*)d_ws;
    unsigned short* buf0  = (unsigned short*)ws;                    // 64MB: x16, later o16
    unsigned short* qkv   = (unsigned short*)(ws + (64ll << 20));   // 192MB
    unsigned short* win16 = (unsigned short*)(ws + (256ll << 20));  // 6MB
    unsigned short* wqkT  = (unsigned short*)(ws + (262ll << 20));  // 2MB
    unsigned short* wvT   = (unsigned short*)(ws + (264ll << 20));  // 2MB
    unsigned short* wbig  = (unsigned short*)(ws + (266ll << 20));  // 6MB  [Wq';Wk';Wv'] bf16
    unsigned short* wo16  = (unsigned short*)(ws + (272ll << 20));  // 2MB
    float*          bbig  = (float*)(ws + (274ll << 20));           // 12KB combined bias
    unsigned short* o16   = buf0;

    // allow 72 KiB dynamic LDS for the ring GEMM (host-side attr, capture-safe)
    hipFuncSetAttribute(reinterpret_cast<const void*>(&gemm256x128<false>),
                        hipFuncAttributeMaxDynamicSharedMemorySize, 73728);
    hipFuncSetAttribute(reinterpret_cast<const void*>(&gemm256x128<true>),
                        hipFuncAttributeMaxDynamicSharedMemorySize, 73728);

    dim3 blk(256);
    // dtype prep (x conversion + all weight prep in two dispatches)
    cvt_bf16<<<32768, 256, 0, stream>>>(x, buf0, 8388608);
    prep_w<<<5376, blk, 0, stream>>>(win, win16, wout, wo16,
                                     wqk, wqkT, wv, wvT, bqk, bv, bin, bbig);

    // merged weight fusion: wbig[3072,1024]; rows<2048 use Wqk^T, rows>=2048 use Wv^T
    gemm_bt<false><<<dim3(8, 24), blk, 0, stream>>>(win16, 1024, wqkT, wvT, 2048,
                                                    nullptr, wbig, 1024, 1024);

    // fused projection: qkv[M,3072] = x16 @ W'^T + b'   (M=32768, N=3072, K=1024)
    // grid = 128 bm x 24 bn = 3072 blocks, bm-major XCD-chunked (nbn = 24)
    gemm256x128<false><<<dim3(3072), 512, 73728, stream>>>(buf0, 1024, wbig,
                                                           bbig, qkv, 3072, 1024, 24);

    // attention within 4-token groups (writes o16 = buf0; x16 dead by now)
    attn4<<<8192, blk, 0, stream>>>(qkv, o16);

    // out[M,1024] fp32 = o @ Wo^T + bo   (M=32768, N=1024, K=1024)
    // grid = 128 bm x 8 bn = 1024 blocks, bm-major XCD-chunked (nbn = 8)
    gemm256x128<true><<<dim3(1024), 512, 73728, stream>>>(o16, 1024, wo16,
                                                          bout, d_out, 1024, 1024, 8);
}

// Round 9
// 674.631 us; speedup vs baseline: 1.1176x; 1.1176x over previous
//
#include <hip/hip_runtime.h>
#include <hip/hip_bf16.h>

typedef __bf16 bf16x8 __attribute__((ext_vector_type(8)));
typedef float f32x4 __attribute__((ext_vector_type(4)));

__device__ __forceinline__ float bf2f(unsigned int u) {
    unsigned int x = u << 16;
    return __builtin_bit_cast(float, x);
}
__device__ __forceinline__ unsigned short f2bf(float f) {
    unsigned int x = __builtin_bit_cast(unsigned int, f);
    x += 0x7fffu + ((x >> 16) & 1u);   // RNE
    return (unsigned short)(x >> 16);
}

__device__ __forceinline__ void gld_lds16(const unsigned short* g, unsigned short* s) {
    __builtin_amdgcn_global_load_lds((const __attribute__((address_space(1))) void*)g,
                                     (__attribute__((address_space(3))) void*)s, 16, 0, 0);
}

// ---------------------------------------------------------------------------
// 256x256 ring GEMM, sched-pinned 2-phase cadence (r7: best measured, 297us).
// 8 waves (2M x 4N), 512 threads, BK unit = 32, 4-slot LDS ring (128 KiB).
// Counted close vmcnt(8) (never drain-0 in loop); swizzled LDS (0 conflicts
// measured r1-r8); setprio on MFMA; XCD-chunked bm-major map (FETCH=188MB).
//
// Ring ledger (harness-verified r1/r3/r6/r7):
//  - unit u reads slot u&3; stages unit u+3 into slot (u+3)&3 == (u-1)&3
//    (dead: all its reads drained before unit u-1's close barrier).
//  - close: s_waitcnt vmcnt(8) retires this wave's 4 loads of unit u+1
//    (8 loads of u+2,u+3 in flight); s_barrier makes it collective.
//  - post-loop vmcnt(0): nothing in flight at endpgm.
// ---------------------------------------------------------------------------
template<bool OUT_F32>
__global__ __launch_bounds__(512) void gemm256(
    const unsigned short* __restrict__ A, int lda,
    const unsigned short* __restrict__ B,
    const float* __restrict__ bias,
    void* __restrict__ C, int N, int K, int nx)
{
    extern __shared__ char smem[];
    const int tid   = threadIdx.x;
    const int lane  = tid & 63;
    const int wave  = tid >> 6;
    const int wm    = (wave >> 2) * 128;   // 2 M-positions
    const int wn    = (wave & 3) * 64;     // 4 N-positions
    const int lrow  = lane & 15;
    const int lquad = lane >> 4;

    int L = (int)blockIdx.x;
    L = (L & 7) * ((int)gridDim.x >> 3) + (L >> 3);
    const long bm = (long)(L / nx) * 256;
    const long bn = (long)(L % nx) * 256;

    // staging source mapping (inverse of the read swizzle)
    const int srow = (lane & 7) + ((lane >> 5) << 3);
    const int scol = ((lane >> 3) & 3) * 8;
    const unsigned short* Asrc0 = A + (bm + wave * 16 + srow) * (long)lda + scol;
    const unsigned short* Asrc1 = A + (bm + (8 + wave) * 16 + srow) * (long)lda + scol;
    const unsigned short* Bsrc0 = B + (bn + wave * 16 + srow) * (long)K + scol;
    const unsigned short* Bsrc1 = B + (bn + (8 + wave) * 16 + srow) * (long)K + scol;

    const int dA0 = wave * 1024 + lane * 16;
    const int dA1 = (8 + wave) * 1024 + lane * 16;
    const int dB0 = 16384 + dA0;
    const int dB1 = 16384 + dA1;

    const int rdoff = (lrow & 7) * 16 + (lrow >> 3) * 512 + lquad * 128;

    f32x4 acc[8][4];
#pragma unroll
    for (int i = 0; i < 8; i++)
#pragma unroll
        for (int j = 0; j < 4; j++)
            acc[i][j] = (f32x4){0.f, 0.f, 0.f, 0.f};

    const int NU = K >> 5;   // K units of 32 (requires NU >= 4)

    auto stageA = [&](int su, int slot) {
        char* sb = smem + (size_t)(slot * 32768);
        gld_lds16(Asrc0 + su * 32, (unsigned short*)(sb + dA0));
        gld_lds16(Asrc1 + su * 32, (unsigned short*)(sb + dA1));
    };
    auto stageB = [&](int su, int slot) {
        char* sb = smem + (size_t)(slot * 32768);
        gld_lds16(Bsrc0 + su * 32, (unsigned short*)(sb + dB0));
        gld_lds16(Bsrc1 + su * 32, (unsigned short*)(sb + dB1));
    };

    // prologue: stage units 0,1,2 into slots 0,1,2; wait only for unit 0
    stageA(0, 0); stageB(0, 0);
    stageA(1, 1); stageB(1, 1);
    stageA(2, 2); stageB(2, 2);
    asm volatile("s_waitcnt vmcnt(8)\n\ts_barrier" ::: "memory");

    for (int u = 0; u < NU; ++u) {
        char* sl = smem + (size_t)((u & 3) * 32768);
        const int us   = (u + 3 < NU) ? (u + 3) : (NU - 1);  // clamped tail stage
        const int slot = (u + 3) & 3;                        // dest slot is the DEAD one
        bf16x8 af0[4], af1[4], bq[4];

        // ---- phase A: {bq + af0 ds_reads, stage A-half} | bar | lgkm0 | 16 MFMA ----
#pragma unroll
        for (int j = 0; j < 4; j++)
            bq[j] = *(const bf16x8*)(sl + 16384 + ((wn >> 4) + j) * 1024 + rdoff);
#pragma unroll
        for (int i = 0; i < 4; i++)
            af0[i] = *(const bf16x8*)(sl + ((wm >> 4) + i) * 1024 + rdoff);
        stageA(us, slot);
        __builtin_amdgcn_sched_barrier(0);
        __builtin_amdgcn_s_barrier();
        asm volatile("s_waitcnt lgkmcnt(0)" ::: "memory");
        __builtin_amdgcn_sched_barrier(0);
        __builtin_amdgcn_s_setprio(1);
#pragma unroll
        for (int i = 0; i < 4; i++)
#pragma unroll
            for (int j = 0; j < 4; j++)
                acc[i][j] = __builtin_amdgcn_mfma_f32_16x16x32_bf16(bq[j], af0[i], acc[i][j], 0, 0, 0);
        __builtin_amdgcn_s_setprio(0);
        __builtin_amdgcn_sched_barrier(0);
        __builtin_amdgcn_s_barrier();

        // ---- phase B: {af1 ds_reads, stage B-half} | bar | lgkm0 | 16 MFMA | close ----
#pragma unroll
        for (int i = 0; i < 4; i++)
            af1[i] = *(const bf16x8*)(sl + ((wm >> 4) + 4 + i) * 1024 + rdoff);
        stageB(us, slot);
        __builtin_amdgcn_sched_barrier(0);
        __builtin_amdgcn_s_barrier();
        asm volatile("s_waitcnt lgkmcnt(0)" ::: "memory");
        __builtin_amdgcn_sched_barrier(0);
        __builtin_amdgcn_s_setprio(1);
#pragma unroll
        for (int i = 0; i < 4; i++)
#pragma unroll
            for (int j = 0; j < 4; j++)
                acc[4 + i][j] = __builtin_amdgcn_mfma_f32_16x16x32_bf16(bq[j], af1[i], acc[4 + i][j], 0, 0, 0);
        __builtin_amdgcn_s_setprio(0);
        __builtin_amdgcn_sched_barrier(0);
        // counted close: units u+2,u+3 stay in flight; unit u+1 is landed
        asm volatile("s_waitcnt vmcnt(8)\n\ts_barrier" ::: "memory");
    }

    // drain clamped tail stages: no LDS-writing load in flight at endpgm
    asm volatile("s_waitcnt vmcnt(0)" ::: "memory");

    // Swapped C/D layout: M-row = lane&15 (+i*16), N-col = quad*4 + reg (+j*16).
#pragma unroll
    for (int i = 0; i < 8; i++) {
        const long row = bm + wm + i * 16 + lrow;
#pragma unroll
        for (int j = 0; j < 4; j++) {
            const int colb = (int)bn + wn + j * 16 + lquad * 4;
            float4 b4 = bias ? ((const float4*)bias)[colb >> 2]
                             : make_float4(0.f, 0.f, 0.f, 0.f);
            const float v0 = acc[i][j][0] + b4.x;
            const float v1 = acc[i][j][1] + b4.y;
            const float v2 = acc[i][j][2] + b4.z;
            const float v3 = acc[i][j][3] + b4.w;
            if (OUT_F32) {
                *(float4*)&((float*)C)[row * (long)N + colb] = make_float4(v0, v1, v2, v3);
            } else {
                unsigned int lo = (unsigned int)f2bf(v0) | ((unsigned int)f2bf(v1) << 16);
                unsigned int hi = (unsigned int)f2bf(v2) | ((unsigned int)f2bf(v3) << 16);
                *(uint2*)&((unsigned short*)C)[row * (long)N + colb] = make_uint2(lo, hi);
            }
        }
    }
}

// ---------------------------------------------------------------------------
// 128x128 ring GEMM with B/B2 row-split — replaces the old conflicted,
// prefetch-free gemm_bt for the small weight-fusion GEMM (192 blocks).
// r4-harness-verified structure: 4 waves (2x2), 3-slot 48 KiB ring, counted
// vmcnt(4) close, region swizzle (0 conflicts). At this tiny grid the r4
// failure mode (L2 thrash at 6144 blocks) does not apply: A=6MB, B=2+2MB
// are L2/L3 resident. Only addition vs r4: Bp = (bm>=bsplit)?B2:B (same
// semantics as the old gemm_bt; bsplit=2048 is tile-aligned).
// ---------------------------------------------------------------------------
__global__ __launch_bounds__(256, 3) void gemm128f(
    const unsigned short* __restrict__ A, int lda,
    const unsigned short* __restrict__ B,
    const unsigned short* __restrict__ B2, long bsplit,
    unsigned short* __restrict__ C, int N, int K, int nbn)
{
    __shared__ uint4 smem4[3072];              // 49152 B = 3 slots x 16 KiB
    char* smem = (char*)smem4;
    const int tid   = threadIdx.x;
    const int lane  = tid & 63;
    const int wave  = tid >> 6;                // 0..3
    const int wm    = (wave >> 1) * 64;
    const int wn    = (wave & 1) * 64;
    const int lrow  = lane & 15;
    const int lquad = lane >> 4;

    int L = (int)blockIdx.x;
    L = (L & 7) * ((int)gridDim.x >> 3) + (L >> 3);
    const long bm = (long)(L / nbn) * 128;
    const long bn = (long)(L % nbn) * 128;
    const unsigned short* Bp = (bm >= bsplit) ? B2 : B;

    const int srow = (lane & 7) + ((lane >> 5) << 3);
    const int scol = ((lane >> 3) & 3) * 8;
    const unsigned short* Ag0 = A + (bm + wave * 16 + srow) * (long)lda + scol;
    const unsigned short* Ag1 = A + (bm + (wave + 4) * 16 + srow) * (long)lda + scol;
    const unsigned short* Bg0 = Bp + (bn + wave * 16 + srow) * (long)K + scol;
    const unsigned short* Bg1 = Bp + (bn + (wave + 4) * 16 + srow) * (long)K + scol;

    const int dA0 = wave * 1024 + lane * 16;
    const int dA1 = dA0 + 4096;
    const int dB0 = 8192 + dA0;
    const int dB1 = 8192 + dA1;

    const int rdoff = (lrow & 7) * 16 + (lrow >> 3) * 512 + lquad * 128;

    f32x4 acc[4][4];
#pragma unroll
    for (int i = 0; i < 4; i++)
#pragma unroll
        for (int j = 0; j < 4; j++)
            acc[i][j] = (f32x4){0.f, 0.f, 0.f, 0.f};

    const int NU = K >> 5;   // requires NU >= 3

    auto stage = [&](int su, char* sb) {
        gld_lds16(Ag0 + su * 32, (unsigned short*)(sb + dA0));
        gld_lds16(Ag1 + su * 32, (unsigned short*)(sb + dA1));
        gld_lds16(Bg0 + su * 32, (unsigned short*)(sb + dB0));
        gld_lds16(Bg1 + su * 32, (unsigned short*)(sb + dB1));
    };

    stage(0, smem);
    stage(1, smem + 16384);
    asm volatile("s_waitcnt vmcnt(4)\n\ts_barrier" ::: "memory");

    int cs = 0, ws = 2;
    for (int u = 0; u < NU; ++u) {
        const char* sl = smem + cs * 16384;
        char* sw = smem + ws * 16384;
        const int us = (u + 2 < NU) ? (u + 2) : (NU - 1);
        bf16x8 af[4], bq[4];

#pragma unroll
        for (int j = 0; j < 4; j++)
            bq[j] = *(const bf16x8*)(sl + 8192 + ((wn >> 4) + j) * 1024 + rdoff);
#pragma unroll
        for (int i = 0; i < 4; i++)
            af[i] = *(const bf16x8*)(sl + ((wm >> 4) + i) * 1024 + rdoff);
        stage(us, sw);

        __builtin_amdgcn_s_setprio(1);
#pragma unroll
        for (int i = 0; i < 4; i++)
#pragma unroll
            for (int j = 0; j < 4; j++)
                acc[i][j] = __builtin_amdgcn_mfma_f32_16x16x32_bf16(bq[j], af[i], acc[i][j], 0, 0, 0);
        __builtin_amdgcn_s_setprio(0);

        asm volatile("s_waitcnt vmcnt(4)\n\ts_barrier" ::: "memory");
        cs = (cs == 2) ? 0 : cs + 1;
        ws = (ws == 2) ? 0 : ws + 1;
    }

    asm volatile("s_waitcnt vmcnt(0)" ::: "memory");

#pragma unroll
    for (int i = 0; i < 4; i++) {
        const long row = bm + wm + i * 16 + lrow;
#pragma unroll
        for (int j = 0; j < 4; j++) {
            const int colb = (int)bn + wn + j * 16 + lquad * 4;
            unsigned int lo = (unsigned int)f2bf(acc[i][j][0]) | ((unsigned int)f2bf(acc[i][j][1]) << 16);
            unsigned int hi = (unsigned int)f2bf(acc[i][j][2]) | ((unsigned int)f2bf(acc[i][j][3]) << 16);
            *(uint2*)&C[row * (long)N + colb] = make_uint2(lo, hi);
        }
    }
}

// Per (group,head): 4x4 scores over hd=128, diag masked, softmax, o = A@v.
__global__ __launch_bounds__(256) void attn4(
    const unsigned short* __restrict__ QKV,  // [M][3072]: q|k|v
    unsigned short* __restrict__ O)          // [M][1024]
{
    const int wave = threadIdx.x >> 6;
    const int lane = threadIdx.x & 63;
    const int half = lane >> 5;
    const int l    = lane & 31;
    const int gh = blockIdx.x * 8 + wave * 2 + half;  // 0..65535
    const int g = gh >> 3, h = gh & 7;
    const long row0 = (long)g * 4;
    const int d0 = h * 128 + l * 4;
    const float scale = 0.08838834764831845f;  // 1/sqrt(128)

    float q[4][4], k[4][4], v[4][4];
#pragma unroll
    for (int i = 0; i < 4; i++) {
        const unsigned short* base = QKV + (row0 + i) * 3072 + d0;
        uint2 uq = *(const uint2*)base;
        uint2 uk = *(const uint2*)(base + 1024);
        uint2 uv = *(const uint2*)(base + 2048);
        q[i][0] = bf2f(uq.x & 0xffffu); q[i][1] = bf2f(uq.x >> 16);
        q[i][2] = bf2f(uq.y & 0xffffu); q[i][3] = bf2f(uq.y >> 16);
        k[i][0] = bf2f(uk.x & 0xffffu); k[i][1] = bf2f(uk.x >> 16);
        k[i][2] = bf2f(uk.y & 0xffffu); k[i][3] = bf2f(uk.y >> 16);
        v[i][0] = bf2f(uv.x & 0xffffu); v[i][1] = bf2f(uv.x >> 16);
        v[i][2] = bf2f(uv.y & 0xffffu); v[i][3] = bf2f(uv.y >> 16);
    }
    float s[4][4];
#pragma unroll
    for (int i = 0; i < 4; i++)
#pragma unroll
        for (int j = 0; j < 4; j++)
            s[i][j] = q[i][0] * k[j][0] + q[i][1] * k[j][1]
                    + q[i][2] * k[j][2] + q[i][3] * k[j][3];
#pragma unroll
    for (int m = 1; m < 32; m <<= 1)
#pragma unroll
        for (int i = 0; i < 4; i++)
#pragma unroll
            for (int j = 0; j < 4; j++)
                s[i][j] += __shfl_xor(s[i][j], m, 64);

#pragma unroll
    for (int i = 0; i < 4; i++) {
        float mx = -3.0e38f;
#pragma unroll
        for (int j = 0; j < 4; j++)
            if (j != i) mx = fmaxf(mx, s[i][j] * scale);
        float p[4], den = 0.f;
#pragma unroll
        for (int j = 0; j < 4; j++) {
            p[j] = (j == i) ? 0.f : __expf(s[i][j] * scale - mx);
            den += p[j];
        }
        const float inv = 1.f / den;
        float o0 = 0.f, o1 = 0.f, o2 = 0.f, o3 = 0.f;
#pragma unroll
        for (int j = 0; j < 4; j++) {
            const float a = p[j] * inv;
            o0 += a * v[j][0]; o1 += a * v[j][1];
            o2 += a * v[j][2]; o3 += a * v[j][3];
        }
        unsigned int lo = (unsigned int)f2bf(o0) | ((unsigned int)f2bf(o1) << 16);
        unsigned int hi = (unsigned int)f2bf(o2) | ((unsigned int)f2bf(o3) << 16);
        *(uint2*)(O + (row0 + i) * 1024 + d0) = make_uint2(lo, hi);
    }
}

// One dispatch for ALL prep (x cvt + weight cvt + transposes + bias fusion):
//   [0, 32768)       : cvt x (fp32 -> bf16), 8388608 float4s
//   [32768, 36864)   : cvt win -> win16 then wout -> wo16
//   [36864, 37376)   : transpose+cvt wqk -> wqkT / wv -> wvT (64x64 tiles)
//   [37376, 38144)   : bbig[row] = dot(win[row,:], row<2048?bqk:bv) + bin[row]
__global__ __launch_bounds__(256) void prep_all(
    const float* __restrict__ x,    unsigned short* __restrict__ x16,
    const float* __restrict__ win,  unsigned short* __restrict__ win16,
    const float* __restrict__ wout, unsigned short* __restrict__ wo16,
    const float* __restrict__ wqk,  unsigned short* __restrict__ wqkT,
    const float* __restrict__ wv,   unsigned short* __restrict__ wvT,
    const float* __restrict__ bqk,  const float* __restrict__ bv,
    const float* __restrict__ bin,  float* __restrict__ bbig)
{
    __shared__ unsigned short tile[64][65];
    const int bid = blockIdx.x;
    if (bid < 32768) {
        int i = bid * 256 + threadIdx.x;
        float4 v = ((const float4*)x)[i];
        unsigned int a = (unsigned int)f2bf(v.x) | ((unsigned int)f2bf(v.y) << 16);
        unsigned int b = (unsigned int)f2bf(v.z) | ((unsigned int)f2bf(v.w) << 16);
        ((uint2*)x16)[i] = make_uint2(a, b);
    } else if (bid < 36864) {
        int i = (bid - 32768) * 256 + threadIdx.x;
        const float* in;
        unsigned short* out;
        int j;
        if (i < 786432) { in = win; out = win16; j = i; }
        else            { in = wout; out = wo16; j = i - 786432; }
        float4 v = ((const float4*)in)[j];
        unsigned int a = (unsigned int)f2bf(v.x) | ((unsigned int)f2bf(v.y) << 16);
        unsigned int b = (unsigned int)f2bf(v.z) | ((unsigned int)f2bf(v.w) << 16);
        ((uint2*)out)[j] = make_uint2(a, b);
    } else if (bid < 37376) {
        const int b2 = bid - 36864;
        const int z = b2 >> 8, rem = b2 & 255;
        const int bx = (rem & 15) * 64, by = (rem >> 4) * 64;
        const float* in = z ? wv : wqk;
        unsigned short* out = z ? wvT : wqkT;
        const int tx = threadIdx.x & 63, ty = threadIdx.x >> 6;
        for (int r = ty; r < 64; r += 4)
            tile[r][tx] = f2bf(in[(long)(by + r) * 1024 + bx + tx]);
        __syncthreads();
        for (int r = ty; r < 64; r += 4)
            out[(long)(bx + r) * 1024 + by + tx] = tile[tx][r];
    } else {
        const int row = (bid - 37376) * 4 + (threadIdx.x >> 6);
        const int lane = threadIdx.x & 63;
        const float* b = (row < 2048) ? bqk : bv;
        float s = 0.f;
        for (int t = lane; t < 1024; t += 64) s += win[(long)row * 1024 + t] * b[t];
#pragma unroll
        for (int m = 1; m < 64; m <<= 1) s += __shfl_xor(s, m, 64);
        if (lane == 0) bbig[row] = s + bin[row];
    }
}

extern "C" void kernel_launch(void* const* d_in, const int* in_sizes, int n_in,
                              void* d_out, int out_size, void* d_ws, size_t ws_size,
                              hipStream_t stream)
{
    (void)in_sizes; (void)n_in; (void)out_size; (void)ws_size;
    const float* x    = (const float*)d_in[0];
    const float* wqk  = (const float*)d_in[1];
    const float* bqk  = (const float*)d_in[2];
    const float* wv   = (const float*)d_in[3];
    const float* bv   = (const float*)d_in[4];
    const float* win  = (const float*)d_in[5];
    const float* bin  = (const float*)d_in[6];
    const float* wout = (const float*)d_in[7];
    const float* bout = (const float*)d_in[8];

    char* ws = (char*)d_ws;
    unsigned short* buf0  = (unsigned short*)ws;                    // 64MB: x16, later o16
    unsigned short* qkv   = (unsigned short*)(ws + (64ll << 20));   // 192MB
    unsigned short* win16 = (unsigned short*)(ws + (256ll << 20));  // 6MB
    unsigned short* wqkT  = (unsigned short*)(ws + (262ll << 20));  // 2MB
    unsigned short* wvT   = (unsigned short*)(ws + (264ll << 20));  // 2MB
    unsigned short* wbig  = (unsigned short*)(ws + (266ll << 20));  // 6MB  [Wq';Wk';Wv'] bf16
    unsigned short* wo16  = (unsigned short*)(ws + (272ll << 20));  // 2MB
    float*          bbig  = (float*)(ws + (274ll << 20));           // 12KB combined bias
    unsigned short* o16   = buf0;

    // allow 128 KiB dynamic LDS for the ring GEMM (host-side attr, capture-safe)
    hipFuncSetAttribute(reinterpret_cast<const void*>(&gemm256<false>),
                        hipFuncAttributeMaxDynamicSharedMemorySize, 131072);
    hipFuncSetAttribute(reinterpret_cast<const void*>(&gemm256<true>),
                        hipFuncAttributeMaxDynamicSharedMemorySize, 131072);

    dim3 blk(256);
    // all dtype/weight prep in ONE dispatch
    prep_all<<<38144, blk, 0, stream>>>(x, buf0, win, win16, wout, wo16,
                                        wqk, wqkT, wv, wvT, bqk, bv, bin, bbig);

    // merged weight fusion: wbig[3072,1024]; rows<2048 use Wqk^T, rows>=2048 use Wv^T
    // grid = 24 bm x 8 bn = 192 blocks (ring kernel, prefetch depth 2)
    gemm128f<<<dim3(192), blk, 0, stream>>>(win16, 1024, wqkT, wvT, 2048,
                                            wbig, 1024, 1024, 8);

    // fused projection: qkv[M,3072] = x16 @ W'^T + b'   (M=32768, N=3072, K=1024)
    // grid = 128 bm x 12 bn, bm-major XCD-chunked mapping (nx = 12)
    gemm256<false><<<dim3(1536), 512, 131072, stream>>>(buf0, 1024, wbig,
                                                        bbig, qkv, 3072, 1024, 12);

    // attention within 4-token groups (writes o16 = buf0; x16 dead by now)
    attn4<<<8192, blk, 0, stream>>>(qkv, o16);

    // out[M,1024] fp32 = o @ Wo^T + bo   (M=32768, N=1024, K=1024)
    // grid = 128 bm x 4 bn, bm-major XCD-chunked mapping (nx = 4)
    gemm256<true><<<dim3(512), 512, 131072, stream>>>(o16, 1024, wo16,
                                                      bout, d_out, 1024, 1024, 4);
}